// Round 9
// baseline (456.398 us; speedup 1.0000x reference)
//
#include <hip/hip_runtime.h>
#include <stdint.h>
#include <stddef.h>

typedef unsigned short u16;
typedef __bf16 bf16x8 __attribute__((ext_vector_type(8)));
typedef float f32x4 __attribute__((ext_vector_type(4)));

#define DEV __device__ __forceinline__

DEV float bf2f(u16 u){ union{uint32_t i; float f;} c; c.i=(uint32_t)u<<16; return c.f; }
DEV u16 f2bf(float f){ union{float f; uint32_t i;} c; c.f=f; uint32_t x=c.i;
  uint32_t r = x + 0x7FFFu + ((x>>16)&1u); return (u16)(r>>16); }
DEV uint32_t fmap(float f){ union{float f; uint32_t u;} c; c.f=f;
  return (c.u & 0x80000000u) ? ~c.u : (c.u | 0x80000000u); }
DEV float funmap(uint32_t u){ union{uint32_t u; float f;} c;
  c.u = (u & 0x80000000u) ? (u & 0x7FFFFFFFu) : ~u; return c.f; }
DEV void split2(float x, u16& h, u16& l){ h = f2bf(x); l = f2bf(x - bf2f(h)); }

// ---- block reductions (256 threads = 4 waves) ----
DEV float bredsum(float v, float* buf, int tid){
  #pragma unroll
  for(int o=32;o;o>>=1) v += __shfl_down(v,o);
  __syncthreads();
  if((tid&63)==0) buf[tid>>6]=v;
  __syncthreads();
  return buf[0]+buf[1]+buf[2]+buf[3];
}
// ---- wave helpers ----
DEV int wexscan(int v, int lane){
  int x = v;
  #pragma unroll
  for(int o=1;o<64;o<<=1){ int t = __shfl_up(x,o); if(lane>=o) x += t; }
  return x - v;
}

// ============================================================================
// 64x128-tile plain bf16 GEMM. 4 waves: wave = 32(M)x64(N), acc[2][4].
// SK>1: K sliced by blockIdx.z, fp32 partials (no bias/act).
// SK==1: full epilogue (scale, bias, act, bf16/fp32 writes).
// ============================================================================
template<bool RELU, int SK>
__global__ __launch_bounds__(256)
void gemm1_64(const u16* __restrict__ A, int lda,
              const u16* __restrict__ Bt, int ldb,
              const float* __restrict__ bias, float scale,
              u16* __restrict__ outb, float* __restrict__ outf,
              float* __restrict__ part,
              int K, int ldc, int M)
{
  __shared__ __align__(16) u16 As[64*32];
  __shared__ __align__(16) u16 Bs[128*32];
  const int tid = threadIdx.x, lane = tid&63, wave = tid>>6;
  const int m0 = blockIdx.y*64, n0 = blockIdx.x*128;
  const int wm = (wave>>1)*32, wn = (wave&1)*64;
  const int ml = lane&15, quad = lane>>4;
  const int ks = K / SK;
  const int kbeg = blockIdx.z * ks;
  const u16* pa  = A  + (size_t)(m0+(tid>>2))*lda + kbeg + (tid&3)*8;
  const u16* pb0 = Bt + (size_t)(n0+(tid>>2))*ldb + kbeg + (tid&3)*8;
  const u16* pb1 = Bt + (size_t)(n0+64+(tid>>2))*ldb + kbeg + (tid&3)*8;

  f32x4 acc[2][4];
  #pragma unroll
  for(int i=0;i<2;i++)
    #pragma unroll
    for(int j=0;j<4;j++) acc[i][j] = (f32x4){0.f,0.f,0.f,0.f};

  uint4 ra=*(const uint4*)pa, rb0=*(const uint4*)pb0, rb1=*(const uint4*)pb1;
  for(int k0=0;k0<ks;k0+=32){
    __syncthreads();
    *(uint4*)&As[tid*8]       = ra;
    *(uint4*)&Bs[tid*8]       = rb0;
    *(uint4*)&Bs[(256+tid)*8] = rb1;
    __syncthreads();
    if(k0+32<ks){
      ra  = *(const uint4*)(pa +k0+32);
      rb0 = *(const uint4*)(pb0+k0+32);
      rb1 = *(const uint4*)(pb1+k0+32);
    }
    bf16x8 af[2], bf[4];
    #pragma unroll
    for(int mi=0;mi<2;mi++) af[mi] = *(const bf16x8*)&As[(wm+mi*16+ml)*32 + quad*8];
    #pragma unroll
    for(int ni=0;ni<4;ni++) bf[ni] = *(const bf16x8*)&Bs[(wn+ni*16+ml)*32 + quad*8];
    #pragma unroll
    for(int mi=0;mi<2;mi++)
      #pragma unroll
      for(int ni=0;ni<4;ni++)
        acc[mi][ni] = __builtin_amdgcn_mfma_f32_16x16x32_bf16(af[mi], bf[ni], acc[mi][ni], 0,0,0);
  }
  // C/D: col = lane&15, row = quad*4 + reg  (m89-verified)
  #pragma unroll
  for(int mi=0;mi<2;mi++){
    const int rbase = m0 + wm + mi*16 + quad*4;
    #pragma unroll
    for(int ni=0;ni<4;ni++){
      const int col = n0 + wn + ni*16 + ml;
      if(SK==1){
        const float bv = bias ? bias[col] : 0.f;
        #pragma unroll
        for(int r=0;r<4;r++){
          float v = acc[mi][ni][r]*scale + bv;
          if(RELU) v = fmaxf(v, 0.f);
          const size_t idx = (size_t)(rbase + r)*ldc + col;
          if(outb) outb[idx] = f2bf(v);
          if(outf) outf[idx] = v;
        }
      }else{
        #pragma unroll
        for(int r=0;r<4;r++)
          part[((size_t)blockIdx.z*M + rbase + r)*ldc + col] = acc[mi][ni][r];
      }
    }
  }
}

// ============================================================================
// 64x128-tile split-bf16 GEMM (fp32-class, 3 MFMAs/step). Same SK scheme.
// ============================================================================
template<bool RELU, int SK>
__global__ __launch_bounds__(256)
void gemm3_64(const u16* __restrict__ Ah, const u16* __restrict__ Al, int lda,
              const u16* __restrict__ Bh, const u16* __restrict__ Bl, int ldb,
              const float* __restrict__ bias, float scale,
              u16* __restrict__ outh, u16* __restrict__ outl,
              float* __restrict__ outf, float* __restrict__ part,
              int K, int ldc, int M)
{
  __shared__ __align__(16) u16 AsH[64*32];
  __shared__ __align__(16) u16 AsL[64*32];
  __shared__ __align__(16) u16 BsH[128*32];
  __shared__ __align__(16) u16 BsL[128*32];
  const int tid = threadIdx.x, lane = tid&63, wave = tid>>6;
  const int m0 = blockIdx.y*64, n0 = blockIdx.x*128;
  const int wm = (wave>>1)*32, wn = (wave&1)*64;
  const int ml = lane&15, quad = lane>>4;
  const int ks = K / SK;
  const int kbeg = blockIdx.z * ks;
  const size_t ao  = (size_t)(m0+(tid>>2))*lda + kbeg + (tid&3)*8;
  const size_t bo0 = (size_t)(n0+(tid>>2))*ldb + kbeg + (tid&3)*8;
  const size_t bo1 = (size_t)(n0+64+(tid>>2))*ldb + kbeg + (tid&3)*8;

  f32x4 acc[2][4];
  #pragma unroll
  for(int i=0;i<2;i++)
    #pragma unroll
    for(int j=0;j<4;j++) acc[i][j] = (f32x4){0.f,0.f,0.f,0.f};

  uint4 rah=*(const uint4*)(Ah+ao),  ral=*(const uint4*)(Al+ao);
  uint4 rbh0=*(const uint4*)(Bh+bo0), rbl0=*(const uint4*)(Bl+bo0);
  uint4 rbh1=*(const uint4*)(Bh+bo1), rbl1=*(const uint4*)(Bl+bo1);
  for(int k0=0;k0<ks;k0+=32){
    __syncthreads();
    *(uint4*)&AsH[tid*8]       = rah;
    *(uint4*)&AsL[tid*8]       = ral;
    *(uint4*)&BsH[tid*8]       = rbh0;
    *(uint4*)&BsL[tid*8]       = rbl0;
    *(uint4*)&BsH[(256+tid)*8] = rbh1;
    *(uint4*)&BsL[(256+tid)*8] = rbl1;
    __syncthreads();
    if(k0+32<ks){
      const int s = k0+32;
      rah =*(const uint4*)(Ah+ao +s); ral =*(const uint4*)(Al+ao +s);
      rbh0=*(const uint4*)(Bh+bo0+s); rbl0=*(const uint4*)(Bl+bo0+s);
      rbh1=*(const uint4*)(Bh+bo1+s); rbl1=*(const uint4*)(Bl+bo1+s);
    }
    bf16x8 afh[2], afl[2], bfh[4], bfl[4];
    #pragma unroll
    for(int mi=0;mi<2;mi++){
      const int o = (wm+mi*16+ml)*32 + quad*8;
      afh[mi] = *(const bf16x8*)&AsH[o];
      afl[mi] = *(const bf16x8*)&AsL[o];
    }
    #pragma unroll
    for(int ni=0;ni<4;ni++){
      const int o = (wn+ni*16+ml)*32 + quad*8;
      bfh[ni] = *(const bf16x8*)&BsH[o];
      bfl[ni] = *(const bf16x8*)&BsL[o];
    }
    #pragma unroll
    for(int mi=0;mi<2;mi++)
      #pragma unroll
      for(int ni=0;ni<4;ni++){
        acc[mi][ni] = __builtin_amdgcn_mfma_f32_16x16x32_bf16(afh[mi], bfh[ni], acc[mi][ni], 0,0,0);
        acc[mi][ni] = __builtin_amdgcn_mfma_f32_16x16x32_bf16(afh[mi], bfl[ni], acc[mi][ni], 0,0,0);
        acc[mi][ni] = __builtin_amdgcn_mfma_f32_16x16x32_bf16(afl[mi], bfh[ni], acc[mi][ni], 0,0,0);
      }
  }
  #pragma unroll
  for(int mi=0;mi<2;mi++){
    const int rbase = m0 + wm + mi*16 + quad*4;
    #pragma unroll
    for(int ni=0;ni<4;ni++){
      const int col = n0 + wn + ni*16 + ml;
      if(SK==1){
        const float bv = bias ? bias[col] : 0.f;
        #pragma unroll
        for(int r=0;r<4;r++){
          float v = acc[mi][ni][r]*scale + bv;
          if(RELU) v = fmaxf(v, 0.f);
          const size_t idx = (size_t)(rbase + r)*ldc + col;
          if(outh){ u16 h, l; split2(v, h, l); outh[idx] = h; outl[idx] = l; }
          if(outf) outf[idx] = v;
        }
      }else{
        #pragma unroll
        for(int r=0;r<4;r++)
          part[((size_t)blockIdx.z*M + rbase + r)*ldc + col] = acc[mi][ni][r];
      }
    }
  }
}

// ============================================================================
// reduce SK fp32 partials + bias/act -> split-bf16 / bf16 / fp32 outputs.
// ============================================================================
template<bool RELU, int SK>
__global__ __launch_bounds__(256)
void reduce_epi(const float* __restrict__ part, const float* __restrict__ bias,
                float scale, u16* __restrict__ outh, u16* __restrict__ outl,
                u16* __restrict__ outb, float* __restrict__ outf,
                size_t MN, int N)
{
  const size_t i = ((size_t)blockIdx.x*256 + threadIdx.x)*4;
  float4 s = *(const float4*)(part + i);
  #pragma unroll
  for(int z=1; z<SK; z++){
    const float4 t = *(const float4*)(part + (size_t)z*MN + i);
    s.x += t.x; s.y += t.y; s.z += t.z; s.w += t.w;
  }
  const int col = (int)(i % (size_t)N);
  float4 bv = bias ? *(const float4*)(bias + col) : (float4){0.f,0.f,0.f,0.f};
  float v[4] = { s.x*scale + bv.x, s.y*scale + bv.y, s.z*scale + bv.z, s.w*scale + bv.w };
  if(RELU){
    #pragma unroll
    for(int j=0;j<4;j++) v[j] = fmaxf(v[j], 0.f);
  }
  if(outh){
    ushort4 h4, l4;
    split2(v[0], h4.x, l4.x); split2(v[1], h4.y, l4.y);
    split2(v[2], h4.z, l4.z); split2(v[3], h4.w, l4.w);
    *(ushort4*)(outh + i) = h4;
    *(ushort4*)(outl + i) = l4;
  }
  if(outb){
    ushort4 b4;
    b4.x=f2bf(v[0]); b4.y=f2bf(v[1]); b4.z=f2bf(v[2]); b4.w=f2bf(v[3]);
    *(ushort4*)(outb + i) = b4;
  }
  if(outf) *(float4*)(outf + i) = (float4){v[0],v[1],v[2],v[3]};
}

// ============================================================================
// fp32 transpose -> split-bf16 / plain-bf16 ; fp32 -> split-bf16 convert
// ============================================================================
__global__ __launch_bounds__(256)
void transpose_split(const float* __restrict__ in, u16* __restrict__ outh,
                     u16* __restrict__ outl, int R, int C)
{
  __shared__ float tile[32][33];
  const int tx = threadIdx.x & 31, ty = threadIdx.x >> 5;
  const int bx = blockIdx.x*32, by = blockIdx.y*32;
  #pragma unroll
  for(int i=0;i<32;i+=8)
    tile[ty+i][tx] = in[(size_t)(by+ty+i)*C + bx + tx];
  __syncthreads();
  #pragma unroll
  for(int i=0;i<32;i+=8){
    const float v = tile[tx][ty+i];
    u16 h, l; split2(v, h, l);
    const size_t o = (size_t)(bx+ty+i)*R + by + tx;
    outh[o] = h; outl[o] = l;
  }
}
__global__ __launch_bounds__(256)
void transpose_plain(const float* __restrict__ in, u16* __restrict__ outh, int R, int C)
{
  __shared__ float tile[32][33];
  const int tx = threadIdx.x & 31, ty = threadIdx.x >> 5;
  const int bx = blockIdx.x*32, by = blockIdx.y*32;
  #pragma unroll
  for(int i=0;i<32;i+=8)
    tile[ty+i][tx] = in[(size_t)(by+ty+i)*C + bx + tx];
  __syncthreads();
  #pragma unroll
  for(int i=0;i<32;i+=8)
    outh[(size_t)(bx+ty+i)*R + by + tx] = f2bf(tile[tx][ty+i]);
}
__global__ __launch_bounds__(256)
void split_convert(const float* __restrict__ in, u16* __restrict__ oh,
                   u16* __restrict__ ol)
{
  const int i = blockIdx.x*256 + threadIdx.x;
  const float4 v = ((const float4*)in)[i];
  ushort4 h4, l4;
  split2(v.x, h4.x, l4.x); split2(v.y, h4.y, l4.y);
  split2(v.z, h4.z, l4.z); split2(v.w, h4.w, l4.w);
  ((ushort4*)oh)[i] = h4; ((ushort4*)ol)[i] = l4;
}

// ============================================================================
// LayerNorm D=1024 fp32 in -> split-bf16 out
// ============================================================================
__global__ __launch_bounds__(256)
void layernorm_rows(const float* __restrict__ in, const float* __restrict__ g,
                    const float* __restrict__ bb, u16* __restrict__ outh,
                    u16* __restrict__ outl, int ostride)
{
  __shared__ float buf[4];
  const int row = blockIdx.x, tid = threadIdx.x;
  const float4 xv = ((const float4*)(in + (size_t)row*1024))[tid];
  float s  = bredsum(xv.x+xv.y+xv.z+xv.w, buf, tid);
  float s2 = bredsum(xv.x*xv.x+xv.y*xv.y+xv.z*xv.z+xv.w*xv.w, buf, tid);
  const float mean = s * (1.f/1024.f);
  const float var  = s2 * (1.f/1024.f) - mean*mean;
  const float rs   = 1.f / sqrtf(var + 1e-5f);
  const float4 gv = ((const float4*)g)[tid];
  const float4 bv = ((const float4*)bb)[tid];
  float o0 = (xv.x-mean)*rs*gv.x + bv.x;
  float o1 = (xv.y-mean)*rs*gv.y + bv.y;
  float o2 = (xv.z-mean)*rs*gv.z + bv.z;
  float o3 = (xv.w-mean)*rs*gv.w + bv.w;
  ushort4 oh, ol;
  split2(o0, oh.x, ol.x); split2(o1, oh.y, ol.y);
  split2(o2, oh.z, ol.z); split2(o3, oh.w, ol.w);
  ((ushort4*)(outh + (size_t)row*ostride))[tid] = oh;
  ((ushort4*)(outl + (size_t)row*ostride))[tid] = ol;
}

__global__ __launch_bounds__(256)
void edges_ln(const float* __restrict__ noise, const float* __restrict__ mu,
              const float* __restrict__ lsig, const float* __restrict__ g,
              const float* __restrict__ bb, u16* __restrict__ outh,
              u16* __restrict__ outl, int ostride)
{
  __shared__ float buf[4];
  const int row = blockIdx.x, tid = threadIdx.x;
  const float4 nv  = ((const float4*)(noise + (size_t)row*1024))[tid];
  const float4 muv = ((const float4*)mu)[tid];
  const float4 lsv = ((const float4*)lsig)[tid];
  float v0 = muv.x + expf(lsv.x)*nv.x;
  float v1 = muv.y + expf(lsv.y)*nv.y;
  float v2 = muv.z + expf(lsv.z)*nv.z;
  float v3 = muv.w + expf(lsv.w)*nv.w;
  float s  = bredsum(v0+v1+v2+v3, buf, tid);
  float s2 = bredsum(v0*v0+v1*v1+v2*v2+v3*v3, buf, tid);
  const float mean = s * (1.f/1024.f);
  const float var  = s2 * (1.f/1024.f) - mean*mean;
  const float rs   = 1.f / sqrtf(var + 1e-5f);
  const float4 gv = ((const float4*)g)[tid];
  const float4 bv = ((const float4*)bb)[tid];
  float o0 = (v0-mean)*rs*gv.x + bv.x;
  float o1 = (v1-mean)*rs*gv.y + bv.y;
  float o2 = (v2-mean)*rs*gv.z + bv.z;
  float o3 = (v3-mean)*rs*gv.w + bv.w;
  ushort4 oh, ol;
  split2(o0, oh.x, ol.x); split2(o1, oh.y, ol.y);
  split2(o2, oh.z, ol.z); split2(o3, oh.w, ol.w);
  ((ushort4*)(outh + (size_t)row*ostride))[tid] = oh;
  ((ushort4*)(outl + (size_t)row*ostride))[tid] = ol;
}

// ============================================================================
// softmax(8192)+eps+renorm + top-k_n, ONE WAVE per row. 128 values/lane in
// registers; binary search = pure VALU + shfl (no barriers, no LDS).
// Exact 32-bit threshold; ties: budget, lowest-index-first (slow path only
// when duplicate fp32 values straddle the boundary).
// ============================================================================
__global__ __launch_bounds__(64)
void softmax_topk_a_wave(const float* __restrict__ dots, const int* __restrict__ knp,
                         int* __restrict__ tidx, float* __restrict__ tw)
{
  const int row = blockIdx.x, lane = threadIdx.x;
  const float* x = dots + (size_t)row * 8192;

  uint32_t u[128];
  float mx = -3.4e38f;
  #pragma unroll
  for(int j=0;j<32;j++){            // coalesced: lane*16B, 1KB per instr
    const float4 v = *(const float4*)(x + j*256 + lane*4);
    u[j*4+0] = fmap(v.x); u[j*4+1] = fmap(v.y);
    u[j*4+2] = fmap(v.z); u[j*4+3] = fmap(v.w);
    mx = fmaxf(mx, fmaxf(fmaxf(v.x,v.y), fmaxf(v.z,v.w)));
  }
  #pragma unroll
  for(int o=32;o;o>>=1) mx = fmaxf(mx, __shfl_xor(mx, o));

  float se = 0.f;
  #pragma unroll
  for(int r=0;r<128;r++) se += expf(funmap(u[r]) - mx);
  #pragma unroll
  for(int o=32;o;o>>=1) se += __shfl_xor(se, o);
  const float T = 1.0f + 8192.f*1e-8f;   // sum(softmax)+8192*eps to ~1e-7

  const int k = knp[0];
  // binary search for k-th largest mapped value (exact)
  uint32_t lo = 0u, hi = 0xFFFFFFFFu;
  while(lo < hi){
    const uint32_t mid = lo + ((hi - lo) >> 1) + 1u;
    int c = 0;
    #pragma unroll
    for(int r=0;r<128;r++) c += (u[r] >= mid);
    #pragma unroll
    for(int o=32;o;o>>=1) c += __shfl_xor(c, o);
    if(c >= k) lo = mid; else hi = mid - 1u;
  }
  const uint32_t uth = lo;

  int gt = 0, eq = 0;
  #pragma unroll
  for(int r=0;r<128;r++){ gt += (u[r] > uth); eq += (u[r] == uth); }
  int c1 = gt, ceq = eq;
  #pragma unroll
  for(int o=32;o;o>>=1){ c1 += __shfl_xor(c1, o); ceq += __shfl_xor(ceq, o); }
  const int budget = k - c1;
  const float inv_se = 1.f/se;

  if(budget == ceq){
    // fast path: all threshold-equal elements selected (no duplicates issue)
    const int mysel = gt + eq;
    int slot = row*128 + wexscan(mysel, lane);
    #pragma unroll
    for(int r=0;r<128;r++){
      if(u[r] >= uth){
        const float w = (expf(funmap(u[r]) - mx)*inv_se + 1e-8f)/T;
        tidx[slot] = (r>>2)*256 + lane*4 + (r&3);
        tw[slot] = w;
        slot++;
      }
    }
  }else{
    // slow path (exact duplicates at boundary): re-read row lane-contiguous
    // so global index order == (lane, m) order; take lowest indices first.
    const float* xl = x + lane*128;
    int mygt = 0, myeq = 0;
    for(int m=0;m<128;m++){
      const uint32_t um = fmap(xl[m]);
      mygt += (um > uth); myeq += (um == uth);
    }
    const int eq_before = wexscan(myeq, lane);
    int take = budget - eq_before;
    take = take < 0 ? 0 : (take > myeq ? myeq : take);
    const int mysel = mygt + take;
    int slot = row*128 + wexscan(mysel, lane);
    int taken = 0;
    for(int m=0;m<128;m++){
      const float f = xl[m];
      const uint32_t um = fmap(f);
      bool sel = (um > uth);
      if(um == uth && taken < take){ sel = true; taken++; }
      if(sel){
        const float w = (expf(f - mx)*inv_se + 1e-8f)/T;
        tidx[slot] = lane*128 + m;
        tw[slot] = w;
        slot++;
      }
    }
  }
}

// updates[row] = sum_j w_j * v[idx_j] (v bf16) ; split-bf16 into cat[:,1024:]
__global__ __launch_bounds__(256)
void gather_updates(const int* __restrict__ tidx, const float* __restrict__ tw,
                    const int* __restrict__ knp, const u16* __restrict__ v,
                    u16* __restrict__ cath, u16* __restrict__ catl)
{
  __shared__ int   idx_s[128];
  __shared__ float w_s[128];
  const int row = blockIdx.x, tid = threadIdx.x;
  const int kk = knp[0];
  if(tid < 128){
    idx_s[tid] = (tid < kk) ? (tidx[row*128+tid] & 8191) : 0;
    w_s[tid]   = (tid < kk) ? tw[row*128+tid] : 0.f;
  }
  __syncthreads();
  const int c = tid*4;
  float a0=0,a1=0,a2=0,a3=0;
  for(int j=0;j<kk && j<128;j++){
    const ushort4 vv = *(const ushort4*)&v[(size_t)idx_s[j]*1024 + c];
    const float w = w_s[j];
    a0 += w*bf2f(vv.x); a1 += w*bf2f(vv.y); a2 += w*bf2f(vv.z); a3 += w*bf2f(vv.w);
  }
  ushort4 oh, ol;
  split2(a0, oh.x, ol.x); split2(a1, oh.y, ol.y);
  split2(a2, oh.z, ol.z); split2(a3, oh.w, ol.w);
  ((ushort4*)(cath + (size_t)row*2048 + 1024))[tid] = oh;
  ((ushort4*)(catl + (size_t)row*2048 + 1024))[tid] = ol;
}

// bias_v[m] = dot(bq, k2[m]) / 32   (k2 = split-bf16)
__global__ __launch_bounds__(256)
void bias_v_kernel(const float* __restrict__ bq, const u16* __restrict__ k2h,
                   const u16* __restrict__ k2l, float* __restrict__ out)
{
  __shared__ float buf[4];
  const int row = blockIdx.x, tid = threadIdx.x;
  const ushort4 h4 = ((const ushort4*)(k2h + (size_t)row*1024))[tid];
  const ushort4 l4 = ((const ushort4*)(k2l + (size_t)row*1024))[tid];
  const float4 b4 = ((const float4*)bq)[tid];
  float s = b4.x*(bf2f(h4.x)+bf2f(l4.x)) + b4.y*(bf2f(h4.y)+bf2f(l4.y))
          + b4.z*(bf2f(h4.z)+bf2f(l4.z)) + b4.w*(bf2f(h4.w)+bf2f(l4.w));
  s = bredsum(s, buf, tid);
  if(tid==0) out[row] = s * 0.03125f;
}

// ============================================================================
// H: softmax over 512 + top-k_e mask, one WAVE per row (4 rows/block).
// ============================================================================
__global__ __launch_bounds__(256)
void softmax_topk_h_wave(const float* __restrict__ dv, const int* __restrict__ kep,
                         float* __restrict__ H)
{
  const int wave = threadIdx.x >> 6, lane = threadIdx.x & 63;
  const int row = blockIdx.x*4 + wave;
  const float* x = dv + (size_t)row*512 + lane*8;
  const float4 a = *(const float4*)x;
  const float4 b = *(const float4*)(x+4);
  float vals[8] = {a.x,a.y,a.z,a.w,b.x,b.y,b.z,b.w};

  float mx = vals[0];
  #pragma unroll
  for(int j=1;j<8;j++) mx = fmaxf(mx, vals[j]);
  #pragma unroll
  for(int o=32;o;o>>=1) mx = fmaxf(mx, __shfl_xor(mx, o));
  float e[8], se = 0.f;
  #pragma unroll
  for(int j=0;j<8;j++){ e[j] = expf(vals[j]-mx); se += e[j]; }
  #pragma unroll
  for(int o=32;o;o>>=1) se += __shfl_xor(se, o);
  const float inv = 1.f/se;

  const int k = kep[0];
  unsigned int selmask = 0;
  for(int r=0;r<k;r++){
    unsigned long long best = 0;
    #pragma unroll
    for(int j=0;j<8;j++){
      if(!((selmask>>j)&1u)){
        const unsigned long long key =
          ((unsigned long long)fmap(vals[j]) << 9) | (unsigned long long)(511 - (lane*8+j));
        if(key > best) best = key;
      }
    }
    #pragma unroll
    for(int o=32;o;o>>=1){
      const unsigned long long other = __shfl_xor(best, o);
      if(other > best) best = other;
    }
    const int bidx = 511 - (int)(best & 511ull);
    if((bidx>>3) == lane) selmask |= 1u << (bidx & 7);
  }

  float4 o0, o1;
  o0.x = (selmask&  1u) ? e[0]*inv : 0.f;
  o0.y = (selmask&  2u) ? e[1]*inv : 0.f;
  o0.z = (selmask&  4u) ? e[2]*inv : 0.f;
  o0.w = (selmask&  8u) ? e[3]*inv : 0.f;
  o1.x = (selmask& 16u) ? e[4]*inv : 0.f;
  o1.y = (selmask& 32u) ? e[5]*inv : 0.f;
  o1.z = (selmask& 64u) ? e[6]*inv : 0.f;
  o1.w = (selmask&128u) ? e[7]*inv : 0.f;
  float* outp = H + (size_t)row*512 + lane*8;
  *(float4*)outp     = o0;
  *(float4*)(outp+4) = o1;
}

// ============================================================================
extern "C" void kernel_launch(void* const* d_in, const int* in_sizes, int n_in,
                              void* d_out, int out_size, void* d_ws, size_t ws_size,
                              hipStream_t stream)
{
  const float* inputs = (const float*)d_in[0];
  const float* noise  = (const float*)d_in[1];
  const float* emu    = (const float*)d_in[2];
  const float* elsig  = (const float*)d_in[3];
  const float* Wq = (const float*)d_in[4];  const float* bq = (const float*)d_in[5];
  const float* Wk = (const float*)d_in[6];  const float* bk = (const float*)d_in[7];
  const float* Wv = (const float*)d_in[8];  const float* bv = (const float*)d_in[9];
  const float* W1 = (const float*)d_in[10]; const float* b1 = (const float*)d_in[11];
  const float* W2 = (const float*)d_in[12]; const float* b2 = (const float*)d_in[13];
  const float* g_in = (const float*)d_in[14]; const float* b_in = (const float*)d_in[15];
  const float* g_e  = (const float*)d_in[16]; const float* b_e  = (const float*)d_in[17];
  const int* knp = (const int*)d_in[18];
  const int* kep = (const int*)d_in[19];

  float* out = (float*)d_out;
  float* out_edges = out;                             // 512*1024
  float* out_H     = out + 512*1024;                  // 8192*512
  float* out_dots  = out + 512*1024 + 8192*512;       // 512*8192

  // ---- workspace (~112 MB peak, stream-ordered reuse) ----
  char* p = (char*)d_ws;
  const size_t MB = 1024ull*1024;
  u16* xh = (u16*)(p + 0*MB);            // x split, live to the end (dots_v)
  u16* xl = (u16*)(p + 16*MB);
  u16* kb = (u16*)(p + 32*MB);           // k bf16, dead after dots GEMM
  u16* vb = (u16*)(p + 48*MB);           // v bf16, dead after gather
  float* dotsvf = (float*)(p + 32*MB);   // dots_v fp32 (reuses kb region)
  // weights [64,88)
  u16* WkTh = (u16*)(p + 64*MB);  u16* WkTl = (u16*)(p + 66*MB);
  u16* WvTh = (u16*)(p + 68*MB);
  u16* WqTh = (u16*)(p + 70*MB);
  u16* Wqh  = (u16*)(p + 72*MB);  u16* Wql  = (u16*)(p + 74*MB);   // raw (no T)
  u16* W1Th = (u16*)(p + 76*MB);  u16* W1Tl = (u16*)(p + 80*MB);
  u16* W2Th = (u16*)(p + 84*MB);  u16* W2Tl = (u16*)(p + 86*MB);
  // small [88,102)
  u16* cath = (u16*)(p + 88*MB);  u16* catl = (u16*)(p + 90*MB);
  u16* qmb  = (u16*)(p + 92*MB);
  u16* h1h  = (u16*)(p + 93*MB);  u16* h1l  = (u16*)(p + 94*MB);
  u16* eoh  = (u16*)(p + 95*MB);  u16* eol  = (u16*)(p + 96*MB);
  u16* k2h  = (u16*)(p + 97*MB);  u16* k2l  = (u16*)(p + 98*MB);
  u16* Gth  = (u16*)(p + 99*MB);  u16* Gtl  = (u16*)(p + 100*MB);
  int*   tidx  = (int*)  (p + 101*MB);
  float* tw    = (float*)(p + 101*MB + 256*1024);
  float* biasv = (float*)(p + 101*MB + 512*1024);
  float* part  = (float*)(p + 104*MB);   // split-K partials: 4*512*1024*4 = 8MB

  hipMemsetAsync(tidx, 0, 512ull*128*4, stream);
  hipMemsetAsync(tw,   0, 512ull*128*4, stream);

  // weight prep
  transpose_split<<<dim3(32,32),256,0,stream>>>(Wk, WkTh, WkTl, 1024, 1024);
  transpose_split<<<dim3(32,64),256,0,stream>>>(W1, W1Th, W1Tl, 2048, 1024);
  transpose_split<<<dim3(32,32),256,0,stream>>>(W2, W2Th, W2Tl, 1024, 1024);
  transpose_plain<<<dim3(32,32),256,0,stream>>>(Wv, WvTh, 1024, 1024);
  transpose_plain<<<dim3(32,32),256,0,stream>>>(Wq, WqTh, 1024, 1024);
  split_convert<<<1024,256,0,stream>>>(Wq, Wqh, Wql);

  layernorm_rows<<<8192,256,0,stream>>>(inputs, g_in, b_in, xh, xl, 1024);
  edges_ln<<<512,256,0,stream>>>(noise, emu, elsig, g_e, b_e, cath, catl, 2048);

  const size_t MN = 512ull*1024;
  // --- dots chain (plain bf16; selection-tolerant) ---
  gemm1_64<true,1><<<dim3(8,128),256,0,stream>>>(xh,1024, WkTh,1024, bk, 1.f,
                                                 kb,nullptr, nullptr, 1024,1024,8192);
  gemm1_64<true,1><<<dim3(8,128),256,0,stream>>>(xh,1024, WvTh,1024, bv, 1.f,
                                                 vb,nullptr, nullptr, 1024,1024,8192);
  gemm1_64<false,4><<<dim3(8,8,4),256,0,stream>>>(cath,2048, WqTh,1024, nullptr, 1.f,
                                                  nullptr,nullptr, part, 1024,1024,512);
  reduce_epi<true,4><<<512,256,0,stream>>>(part, bq, 1.f, nullptr,nullptr, qmb,nullptr, MN, 1024);
  gemm1_64<false,1><<<dim3(64,8),256,0,stream>>>(qmb,1024, kb,1024, nullptr, 0.03125f,
                                                 nullptr,out_dots, nullptr, 1024,8192,512);
  softmax_topk_a_wave<<<512,64,0,stream>>>(out_dots, knp, tidx, tw);
  gather_updates<<<512,256,0,stream>>>(tidx, tw, knp, vb, cath, catl);

  // --- edges + H chain (split-bf16, fp32-class), all M=512 -> split-K4 ---
  gemm3_64<false,4><<<dim3(8,8,4),256,0,stream>>>(cath,catl,2048, W1Th,W1Tl,2048,
                                                  nullptr,1.f, nullptr,nullptr,nullptr,
                                                  part, 2048,1024,512);
  reduce_epi<true,4><<<512,256,0,stream>>>(part, b1, 1.f, h1h,h1l, nullptr,nullptr, MN, 1024);
  gemm3_64<false,4><<<dim3(8,8,4),256,0,stream>>>(h1h,h1l,1024, W2Th,W2Tl,1024,
                                                  nullptr,1.f, nullptr,nullptr,nullptr,
                                                  part, 1024,1024,512);
  reduce_epi<false,4><<<512,256,0,stream>>>(part, b2, 1.f, eoh,eol, nullptr,out_edges, MN, 1024);
  gemm3_64<false,4><<<dim3(8,8,4),256,0,stream>>>(eoh,eol,1024, WkTh,WkTl,1024,
                                                  nullptr,1.f, nullptr,nullptr,nullptr,
                                                  part, 1024,1024,512);
  reduce_epi<true,4><<<512,256,0,stream>>>(part, bk, 1.f, k2h,k2l, nullptr,nullptr, MN, 1024);
  gemm3_64<false,4><<<dim3(8,8,4),256,0,stream>>>(k2h,k2l,1024, Wqh,Wql,1024,
                                                  nullptr,1.f, nullptr,nullptr,nullptr,
                                                  part, 1024,1024,512);
  reduce_epi<false,4><<<512,256,0,stream>>>(part, nullptr, 1.f, Gth,Gtl, nullptr,nullptr, MN, 1024);
  bias_v_kernel<<<512,256,0,stream>>>(bq, k2h, k2l, biasv);
  gemm3_64<false,1><<<dim3(4,128),256,0,stream>>>(xh,xl,1024, Gth,Gtl,1024,
                                                  biasv, 0.03125f, nullptr,nullptr,dotsvf,
                                                  nullptr, 1024,512,8192);
  softmax_topk_h_wave<<<2048,256,0,stream>>>(dotsvf, kep, out_H);
}